// Round 3
// baseline (755.012 us; speedup 1.0000x reference)
//
#include <hip/hip_runtime.h>
#include <hip/hip_bf16.h>

// Edgedropping: per-edge MLP score -> sigmoid -> global min/max normalize ->
// mask -> stable stream compaction of edge_index (2 rows) + edge_weight (14 rows).
// OUTPUT BUFFER IS FLOAT32 (outputs are int32+float32 -> "else float*" rule).
// Forensic: bf16 writes into f32 buffer reproduced err 99840+3.609 exactly.

constexpr int BLOCK = 256;
constexpr int CHUNK = 4096;            // edges per count/scatter chunk
constexpr int ROUNDS = CHUNK / BLOCK;  // 16

// ---- scoring ---------------------------------------------------------------
__device__ __forceinline__ float score_edge(const float* we,
                                            const float* sW1, const float* sb1,
                                            const float* sW2,
                                            float b2, float rlog) {
    double acc2 = 0.0;
#pragma unroll
    for (int k = 0; k < 7; ++k) {
        double a = 0.0;
#pragma unroll
        for (int j = 0; j < 14; ++j) a += (double)we[j] * (double)sW1[k * 14 + j];
        float hp = __fadd_rn((float)a, sb1[k]);
        hp = fmaxf(hp, 0.0f);
        acc2 += (double)hp * (double)sW2[k];
    }
    float raw = __fadd_rn((float)acc2, b2);
    float z = __fdiv_rn(__fadd_rn(rlog, raw), 0.05f);
    return __fdiv_rn(1.0f, __fadd_rn(1.0f, expf(-z)));
}

__device__ __forceinline__ bool mask_of(float s, float vmin, float range) {
    float t = __fdiv_rn(__fsub_rn(s, vmin), range);
    float sn = __fadd_rn(__fmul_rn(t, 1.2f), -0.1f);
    return sn > 0.0f;
}

// ---- kernels ---------------------------------------------------------------

__global__ void k_init(unsigned int* minmax) {
    minmax[0] = 0x7F800000u;  // +inf (s>=0 so uint order == float order)
    minmax[1] = 0x00000000u;
}

__global__ void k_compute_s(const float* __restrict__ ew,
                            const float* __restrict__ W1, const float* __restrict__ b1,
                            const float* __restrict__ W2, const float* __restrict__ b2,
                            const float* __restrict__ rl,
                            float* __restrict__ s_out,
                            unsigned int* __restrict__ minmax,
                            long long E) {
    __shared__ float sW1[98], sb1[7], sW2[7];
    __shared__ float sb2, srl;
    int tid = threadIdx.x;
    if (tid < 98) sW1[tid] = W1[tid];
    if (tid < 7) { sb1[tid] = b1[tid]; sW2[tid] = W2[tid]; }
    if (tid == 0) { sb2 = b2[0]; srl = rl[0]; }
    __syncthreads();

    long long nPairs = (E + 1) / 2;
    long long i = (long long)blockIdx.x * blockDim.x + tid;
    float lmin = __uint_as_float(0x7F800000u), lmax = 0.0f;

    if (i < nPairs) {
        float w[28];
        int nE = (2 * i + 1 < E) ? 2 : 1;
        if (nE == 2) {
            const float4* p = (const float4*)ew + i * 7;   // 112B stride, 16B-aligned
#pragma unroll
            for (int q = 0; q < 7; ++q) {
                float4 v = p[q];
                w[4 * q] = v.x; w[4 * q + 1] = v.y; w[4 * q + 2] = v.z; w[4 * q + 3] = v.w;
            }
        } else {
            const float* p = ew + (size_t)(2 * i) * 14;
#pragma unroll
            for (int j = 0; j < 14; ++j) w[j] = p[j];
        }
        for (int h = 0; h < nE; ++h) {
            float s = score_edge(w + 14 * h, sW1, sb1, sW2, sb2, srl);
            s_out[2 * i + h] = s;
            lmin = fminf(lmin, s);
            lmax = fmaxf(lmax, s);
        }
    }
#pragma unroll
    for (int off = 32; off; off >>= 1) {
        lmin = fminf(lmin, __shfl_down(lmin, off));
        lmax = fmaxf(lmax, __shfl_down(lmax, off));
    }
    __shared__ float wmin[4], wmax[4];
    int lane = tid & 63, wid = tid >> 6;
    if (lane == 0) { wmin[wid] = lmin; wmax[wid] = lmax; }
    __syncthreads();
    if (tid == 0) {
        float m0 = wmin[0], M0 = wmax[0];
#pragma unroll
        for (int q = 1; q < 4; ++q) { m0 = fminf(m0, wmin[q]); M0 = fmaxf(M0, wmax[q]); }
        atomicMin(&minmax[0], __float_as_uint(m0));
        atomicMax(&minmax[1], __float_as_uint(M0));
    }
}

__global__ void k_count(const float* __restrict__ s_arr,
                        const unsigned int* __restrict__ minmax,
                        int* __restrict__ counts, long long E) {
    int chunk = blockIdx.x;
    long long base = (long long)chunk * CHUNK;
    float vmin = __uint_as_float(minmax[0]);
    float vmax = __uint_as_float(minmax[1]);
    float range = __fsub_rn(vmax, vmin);
    int tid = threadIdx.x;
    int cnt = 0;
#pragma unroll
    for (int r = 0; r < ROUNDS; ++r) {
        long long e = base + r * BLOCK + tid;
        if (e < E) cnt += mask_of(s_arr[e], vmin, range) ? 1 : 0;
    }
#pragma unroll
    for (int off = 32; off; off >>= 1) cnt += __shfl_down(cnt, off);
    __shared__ int wc[4];
    if ((tid & 63) == 0) wc[tid >> 6] = cnt;
    __syncthreads();
    if (tid == 0) counts[chunk] = wc[0] + wc[1] + wc[2] + wc[3];
}

// single block, 1024 threads, LDS Hillis-Steele; requires nchunks <= 1024
__global__ void k_scan(const int* __restrict__ counts, int* __restrict__ offsets,
                       int nchunks) {
    __shared__ int tmp[1024];
    int tid = threadIdx.x;
    int v = (tid < nchunks) ? counts[tid] : 0;
    tmp[tid] = v;
    for (int off = 1; off < 1024; off <<= 1) {
        __syncthreads();
        int y = (tid >= off) ? tmp[tid - off] : 0;
        __syncthreads();
        tmp[tid] += y;
    }
    if (tid < nchunks) offsets[tid] = tmp[tid] - v;   // exclusive prefix
}

__global__ void k_scatter(const float* __restrict__ s_arr,
                          const unsigned int* __restrict__ minmax,
                          const int* __restrict__ offsets,
                          const int* __restrict__ ei,
                          const float* __restrict__ ew,
                          float* __restrict__ out,
                          long long E, int K) {
    int chunk = blockIdx.x;
    long long base = (long long)chunk * CHUNK;
    int tid = threadIdx.x, lane = tid & 63, wid = tid >> 6;
    float vmin = __uint_as_float(minmax[0]);
    float vmax = __uint_as_float(minmax[1]);
    float range = __fsub_rn(vmax, vmin);

    __shared__ int cnt_rw[ROUNDS][4];
    __shared__ int off_rw[ROUNDS][4];

    // pass 1: per-(round,wave) mask counts
    for (int r = 0; r < ROUNDS; ++r) {
        long long e = base + r * BLOCK + tid;
        bool m = (e < E) && mask_of(s_arr[e], vmin, range);
        unsigned long long bal = __ballot(m);
        if (lane == 0) cnt_rw[r][wid] = (int)__popcll(bal);
    }
    __syncthreads();
    if (tid == 0) {
        int run = 0;
        for (int r = 0; r < ROUNDS; ++r)
            for (int w = 0; w < 4; ++w) { off_rw[r][w] = run; run += cnt_rw[r][w]; }
    }
    __syncthreads();

    int chunk_base = offsets[chunk];
    unsigned long long lt = (lane == 0) ? 0ull : ((1ull << lane) - 1ull);

    // pass 2: write
    for (int r = 0; r < ROUNDS; ++r) {
        long long e = base + r * BLOCK + tid;
        bool m = (e < E) && mask_of(s_arr[e], vmin, range);
        unsigned long long bal = __ballot(m);
        int myrank = __popcll(bal & lt);
        if (m) {
            long long posl = (long long)chunk_base + off_rw[r][wid] + myrank;
            if (posl >= 0 && posl < (long long)K) {
                size_t pos = (size_t)posl;
                size_t Ks = (size_t)K;
                out[pos]      = (float)ei[e];
                out[Ks + pos] = (float)ei[E + e];
#pragma unroll
                for (int rr = 0; rr < 14; ++rr)
                    out[(size_t)(2 + rr) * Ks + pos] = ew[(size_t)rr * E + e];
            }
        }
    }
}

// ---- launch ----------------------------------------------------------------

extern "C" void kernel_launch(void* const* d_in, const int* in_sizes, int n_in,
                              void* d_out, int out_size, void* d_ws, size_t ws_size,
                              hipStream_t stream) {
    const int*   ei = (const int*)d_in[1];
    const float* ew = (const float*)d_in[2];
    const float* W1 = (const float*)d_in[3];
    const float* b1 = (const float*)d_in[4];
    const float* W2 = (const float*)d_in[5];
    const float* b2 = (const float*)d_in[6];
    const float* rl = (const float*)d_in[7];

    long long E = (long long)in_sizes[2] / 14;
    int K = out_size / 16;
    int nchunks = (int)((E + CHUNK - 1) / CHUNK);

    char* ws = (char*)d_ws;
    float*        s_arr   = (float*)ws;
    unsigned int* minmax  = (unsigned int*)(ws + (size_t)E * 4);
    int*          counts  = (int*)(ws + (size_t)E * 4 + 2 * sizeof(unsigned int));
    int*          offsets = counts + nchunks;

    float* out = (float*)d_out;

    k_init<<<1, 1, 0, stream>>>(minmax);

    long long nPairs = (E + 1) / 2;
    int g1 = (int)((nPairs + BLOCK - 1) / BLOCK);
    k_compute_s<<<g1, BLOCK, 0, stream>>>(ew, W1, b1, W2, b2, rl, s_arr, minmax, E);

    k_count<<<nchunks, BLOCK, 0, stream>>>(s_arr, minmax, counts, E);
    k_scan<<<1, 1024, 0, stream>>>(counts, offsets, nchunks);
    k_scatter<<<nchunks, BLOCK, 0, stream>>>(s_arr, minmax, offsets, ei, ew, out, E, K);
}

// Round 4
// 520.926 us; speedup vs baseline: 1.4494x; 1.4494x over previous
//
#include <hip/hip_runtime.h>
#include <hip/hip_bf16.h>

// Edgedropping: per-edge MLP score -> sigmoid -> global min/max normalize ->
// mask -> stable stream compaction of edge_index (2 rows) + edge_weight (14 rows).
// Output buffer: float32.
// R3 lesson: runtime-indexed w[28] spilled to scratch (2.4 GB HBM traffic).
// Fix: named wa[14]/wb[14], all indices compile-time -> registers.

constexpr int BLOCK = 256;
constexpr int CHUNK = 4096;            // edges per count/scatter chunk
constexpr int ROUNDS = CHUNK / BLOCK;  // 16

// ---- scoring (all-constant indexing; numerics identical to R3 pass) --------
__device__ __forceinline__ float score14(const float (&we)[14],
                                         const float* sW1, const float* sb1,
                                         const float* sW2,
                                         float b2, float rlog) {
    double acc2 = 0.0;
#pragma unroll
    for (int k = 0; k < 7; ++k) {
        double a = 0.0;
#pragma unroll
        for (int j = 0; j < 14; ++j) a += (double)we[j] * (double)sW1[k * 14 + j];
        float hp = __fadd_rn((float)a, sb1[k]);
        hp = fmaxf(hp, 0.0f);
        acc2 += (double)hp * (double)sW2[k];
    }
    float raw = __fadd_rn((float)acc2, b2);
    float z = __fdiv_rn(__fadd_rn(rlog, raw), 0.05f);
    return __fdiv_rn(1.0f, __fadd_rn(1.0f, expf(-z)));
}

__device__ __forceinline__ bool mask_of(float s, float vmin, float range) {
    float t = __fdiv_rn(__fsub_rn(s, vmin), range);
    float sn = __fadd_rn(__fmul_rn(t, 1.2f), -0.1f);
    return sn > 0.0f;
}

// ---- kernels ---------------------------------------------------------------

__global__ void k_init(unsigned int* minmax) {
    minmax[0] = 0x7F800000u;  // +inf (s>=0 so uint order == float order)
    minmax[1] = 0x00000000u;
}

__global__ void k_compute_s(const float* __restrict__ ew,
                            const float* __restrict__ W1, const float* __restrict__ b1,
                            const float* __restrict__ W2, const float* __restrict__ b2,
                            const float* __restrict__ rl,
                            float* __restrict__ s_out,
                            unsigned int* __restrict__ minmax,
                            long long E) {
    __shared__ float sW1[98], sb1[7], sW2[7];
    __shared__ float sb2, srl;
    int tid = threadIdx.x;
    if (tid < 98) sW1[tid] = W1[tid];
    if (tid < 7) { sb1[tid] = b1[tid]; sW2[tid] = W2[tid]; }
    if (tid == 0) { sb2 = b2[0]; srl = rl[0]; }
    __syncthreads();

    long long nPairs = (E + 1) / 2;
    long long i = (long long)blockIdx.x * blockDim.x + tid;
    float lmin = __uint_as_float(0x7F800000u), lmax = 0.0f;

    if (i < nPairs) {
        float wa[14], wb[14];
        bool have2 = (2 * i + 1 < E);
        if (have2) {
            const float4* p = (const float4*)ew + (size_t)i * 7;  // 112B stride, 16B-aligned
#pragma unroll
            for (int q = 0; q < 7; ++q) {
                float4 v = p[q];
#pragma unroll
                for (int r = 0; r < 4; ++r) {
                    float f = (r == 0) ? v.x : (r == 1) ? v.y : (r == 2) ? v.z : v.w;
                    int g = 4 * q + r;
                    if (g < 14) wa[g] = f; else wb[g - 14] = f;
                }
            }
        } else {
            const float* p = ew + (size_t)(2 * i) * 14;
#pragma unroll
            for (int j = 0; j < 14; ++j) { wa[j] = p[j]; wb[j] = 0.0f; }
        }
        float s0 = score14(wa, sW1, sb1, sW2, sb2, srl);
        lmin = fminf(lmin, s0);
        lmax = fmaxf(lmax, s0);
        if (have2) {
            float s1 = score14(wb, sW1, sb1, sW2, sb2, srl);
            lmin = fminf(lmin, s1);
            lmax = fmaxf(lmax, s1);
            float2 st; st.x = s0; st.y = s1;
            *(float2*)(s_out + 2 * i) = st;   // 8B-aligned coalesced
        } else {
            s_out[2 * i] = s0;
        }
    }
#pragma unroll
    for (int off = 32; off; off >>= 1) {
        lmin = fminf(lmin, __shfl_down(lmin, off));
        lmax = fmaxf(lmax, __shfl_down(lmax, off));
    }
    __shared__ float wmin[4], wmax[4];
    int lane = tid & 63, wid = tid >> 6;
    if (lane == 0) { wmin[wid] = lmin; wmax[wid] = lmax; }
    __syncthreads();
    if (tid == 0) {
        float m0 = wmin[0], M0 = wmax[0];
#pragma unroll
        for (int q = 1; q < 4; ++q) { m0 = fminf(m0, wmin[q]); M0 = fmaxf(M0, wmax[q]); }
        atomicMin(&minmax[0], __float_as_uint(m0));
        atomicMax(&minmax[1], __float_as_uint(M0));
    }
}

__global__ void k_count(const float* __restrict__ s_arr,
                        const unsigned int* __restrict__ minmax,
                        int* __restrict__ counts, long long E) {
    int chunk = blockIdx.x;
    long long base = (long long)chunk * CHUNK;
    float vmin = __uint_as_float(minmax[0]);
    float vmax = __uint_as_float(minmax[1]);
    float range = __fsub_rn(vmax, vmin);
    int tid = threadIdx.x;
    int cnt = 0;
#pragma unroll
    for (int r = 0; r < ROUNDS; ++r) {
        long long e = base + r * BLOCK + tid;
        if (e < E) cnt += mask_of(s_arr[e], vmin, range) ? 1 : 0;
    }
#pragma unroll
    for (int off = 32; off; off >>= 1) cnt += __shfl_down(cnt, off);
    __shared__ int wc[4];
    if ((tid & 63) == 0) wc[tid >> 6] = cnt;
    __syncthreads();
    if (tid == 0) counts[chunk] = wc[0] + wc[1] + wc[2] + wc[3];
}

// single block, 1024 threads, LDS Hillis-Steele; requires nchunks <= 1024
__global__ void k_scan(const int* __restrict__ counts, int* __restrict__ offsets,
                       int nchunks) {
    __shared__ int tmp[1024];
    int tid = threadIdx.x;
    int v = (tid < nchunks) ? counts[tid] : 0;
    tmp[tid] = v;
    for (int off = 1; off < 1024; off <<= 1) {
        __syncthreads();
        int y = (tid >= off) ? tmp[tid - off] : 0;
        __syncthreads();
        tmp[tid] += y;
    }
    if (tid < nchunks) offsets[tid] = tmp[tid] - v;   // exclusive prefix
}

__global__ void k_scatter(const float* __restrict__ s_arr,
                          const unsigned int* __restrict__ minmax,
                          const int* __restrict__ offsets,
                          const int* __restrict__ ei,
                          const float* __restrict__ ew,
                          float* __restrict__ out,
                          long long E, int K) {
    int chunk = blockIdx.x;
    long long base = (long long)chunk * CHUNK;
    int tid = threadIdx.x, lane = tid & 63, wid = tid >> 6;
    float vmin = __uint_as_float(minmax[0]);
    float vmax = __uint_as_float(minmax[1]);
    float range = __fsub_rn(vmax, vmin);

    __shared__ int cnt_rw[ROUNDS][4];
    __shared__ int off_rw[ROUNDS][4];

    // pass 1: per-(round,wave) mask counts
    for (int r = 0; r < ROUNDS; ++r) {
        long long e = base + r * BLOCK + tid;
        bool m = (e < E) && mask_of(s_arr[e], vmin, range);
        unsigned long long bal = __ballot(m);
        if (lane == 0) cnt_rw[r][wid] = (int)__popcll(bal);
    }
    __syncthreads();
    if (tid == 0) {
        int run = 0;
        for (int r = 0; r < ROUNDS; ++r)
            for (int w = 0; w < 4; ++w) { off_rw[r][w] = run; run += cnt_rw[r][w]; }
    }
    __syncthreads();

    int chunk_base = offsets[chunk];
    unsigned long long lt = (lane == 0) ? 0ull : ((1ull << lane) - 1ull);

    // pass 2: write
    for (int r = 0; r < ROUNDS; ++r) {
        long long e = base + r * BLOCK + tid;
        bool m = (e < E) && mask_of(s_arr[e], vmin, range);
        unsigned long long bal = __ballot(m);
        int myrank = __popcll(bal & lt);
        if (m) {
            long long posl = (long long)chunk_base + off_rw[r][wid] + myrank;
            if (posl >= 0 && posl < (long long)K) {
                size_t pos = (size_t)posl;
                size_t Ks = (size_t)K;
                out[pos]      = (float)ei[e];
                out[Ks + pos] = (float)ei[E + e];
#pragma unroll
                for (int rr = 0; rr < 14; ++rr)
                    out[(size_t)(2 + rr) * Ks + pos] = ew[(size_t)rr * E + e];
            }
        }
    }
}

// ---- launch ----------------------------------------------------------------

extern "C" void kernel_launch(void* const* d_in, const int* in_sizes, int n_in,
                              void* d_out, int out_size, void* d_ws, size_t ws_size,
                              hipStream_t stream) {
    const int*   ei = (const int*)d_in[1];
    const float* ew = (const float*)d_in[2];
    const float* W1 = (const float*)d_in[3];
    const float* b1 = (const float*)d_in[4];
    const float* W2 = (const float*)d_in[5];
    const float* b2 = (const float*)d_in[6];
    const float* rl = (const float*)d_in[7];

    long long E = (long long)in_sizes[2] / 14;
    int K = out_size / 16;
    int nchunks = (int)((E + CHUNK - 1) / CHUNK);

    char* ws = (char*)d_ws;
    float*        s_arr   = (float*)ws;
    unsigned int* minmax  = (unsigned int*)(ws + (size_t)E * 4);
    int*          counts  = (int*)(ws + (size_t)E * 4 + 2 * sizeof(unsigned int));
    int*          offsets = counts + nchunks;

    float* out = (float*)d_out;

    k_init<<<1, 1, 0, stream>>>(minmax);

    long long nPairs = (E + 1) / 2;
    int g1 = (int)((nPairs + BLOCK - 1) / BLOCK);
    k_compute_s<<<g1, BLOCK, 0, stream>>>(ew, W1, b1, W2, b2, rl, s_arr, minmax, E);

    k_count<<<nchunks, BLOCK, 0, stream>>>(s_arr, minmax, counts, E);
    k_scan<<<1, 1024, 0, stream>>>(counts, offsets, nchunks);
    k_scatter<<<nchunks, BLOCK, 0, stream>>>(s_arr, minmax, offsets, ei, ew, out, E, K);
}